// Round 1
// baseline (3774.326 us; speedup 1.0000x reference)
//
#include <hip/hip_runtime.h>
#include <hip/hip_bf16.h>
#include <math.h>

// Problem constants (match reference)
constexpr int B_   = 2048;   // sentence pairs
constexpr int L_   = 64;     // leaves per tree
constexpr int V_   = 50000;  // vocab
constexpr int IN_  = 300;    // embedding dim
constexpr int M_   = 150;    // LSTM mem dim
constexpr int HID_ = 50;
constexpr int NC_  = 5;

__device__ __forceinline__ float sgm(float x) { return 1.0f / (1.0f + expf(-x)); }

// ---------------------------------------------------------------------------
// K1: precompute per-vocab leaf h/c tables.
// LeafH[v][m], LeafC[v][m]:  iou = emb[v] @ Wioux + bioux + biouh
//   c = sigmoid(i)*tanh(u); h = sigmoid(o)*tanh(c)
// 32 vocab rows per block, 2 rows per thread iteration to amortize weight loads.
// ---------------------------------------------------------------------------
__global__ __launch_bounds__(256) void leaf_table_kernel(
    const float* __restrict__ emb, const float* __restrict__ Wioux,
    const float* __restrict__ bioux, const float* __restrict__ biouh,
    float* __restrict__ LeafH, float* __restrict__ LeafC)
{
    __shared__ float xs[32 * IN_];   // 38.4 KB
    const int row0 = blockIdx.x * 32;
    const int t = threadIdx.x;

    for (int idx = t; idx < 32 * IN_; idx += 256) {
        const int r = idx / IN_, k = idx % IN_;
        const int v = row0 + r;
        xs[idx] = (v < V_) ? emb[v * IN_ + k] : 0.0f;
    }
    __syncthreads();

    // 16 row-pairs x 150 m-cols = 2400 work items
    for (int p = t; p < 16 * M_; p += 256) {
        const int m  = p % M_;
        const int rp = p / M_;
        const int r0 = 2 * rp, r1 = 2 * rp + 1;
        float ai0 = 0, ao0 = 0, au0 = 0, ai1 = 0, ao1 = 0, au1 = 0;
        for (int k = 0; k < IN_; k++) {
            const float wi = Wioux[k * 450 + m];
            const float wo = Wioux[k * 450 + m + 150];
            const float wu = Wioux[k * 450 + m + 300];
            const float x0 = xs[r0 * IN_ + k];
            const float x1 = xs[r1 * IN_ + k];
            ai0 += x0 * wi; ao0 += x0 * wo; au0 += x0 * wu;
            ai1 += x1 * wi; ao1 += x1 * wo; au1 += x1 * wu;
        }
        const float bi = bioux[m]       + biouh[m];
        const float bo = bioux[m + 150] + biouh[m + 150];
        const float bu = bioux[m + 300] + biouh[m + 300];
        const int v0 = row0 + r0, v1 = row0 + r1;
        if (v0 < V_) {
            const float c = sgm(ai0 + bi) * tanhf(au0 + bu);
            const float h = sgm(ao0 + bo) * tanhf(c);
            LeafH[v0 * M_ + m] = h; LeafC[v0 * M_ + m] = c;
        }
        if (v1 < V_) {
            const float c = sgm(ai1 + bi) * tanhf(au1 + bu);
            const float h = sgm(ao1 + bo) * tanhf(c);
            LeafH[v1 * M_ + m] = h; LeafC[v1 * M_ + m] = c;
        }
    }
}

// ---------------------------------------------------------------------------
// K2: one block per tree (4096 trees). Full 64 -> 1 reduction.
// Level 0 reads children straight from the vocab tables (L3-resident);
// later levels ping-pong f32 h/c state in LDS.
// Two output nodes per thread iteration share the 5 weight loads per k-step.
// ---------------------------------------------------------------------------
__global__ __launch_bounds__(256) void tree_kernel(
    const int* __restrict__ ltok, const int* __restrict__ rtok,
    const float* __restrict__ LeafH, const float* __restrict__ LeafC,
    const float* __restrict__ Wiouh, const float* __restrict__ biouh,
    const float* __restrict__ Wfh, const float* __restrict__ bfh,
    float* __restrict__ RootH)
{
    __shared__ float HB[32 * M_], CB[32 * M_];   // 19.2 KB each
    __shared__ float HA[16 * M_], CA[16 * M_];   //  9.6 KB each  (total 57.6 KB)
    __shared__ int   toks[L_];

    const int b = blockIdx.x;
    const int t = threadIdx.x;
    const int* tok = (b < B_) ? (ltok + b * L_) : (rtok + (b - B_) * L_);
    if (t < L_) toks[t] = tok[t];
    __syncthreads();

    // ---- level 0: 64 leaves -> 32 nodes (children from global tables) ----
    for (int p = t; p < 16 * M_; p += 256) {
        const int m  = p % M_;
        const int np = p / M_;
        const int t0 = toks[4 * np + 0], t1 = toks[4 * np + 1];
        const int t2 = toks[4 * np + 2], t3 = toks[4 * np + 3];
        const float* hl0 = LeafH + t0 * M_;
        const float* hr0 = LeafH + t1 * M_;
        const float* hl1 = LeafH + t2 * M_;
        const float* hr1 = LeafH + t3 * M_;
        float ai0 = 0, ao0 = 0, au0 = 0, fl0 = 0, fr0 = 0;
        float ai1 = 0, ao1 = 0, au1 = 0, fl1 = 0, fr1 = 0;
        for (int k = 0; k < M_; k++) {
            const float wi = Wiouh[k * 450 + m];
            const float wo = Wiouh[k * 450 + m + 150];
            const float wu = Wiouh[k * 450 + m + 300];
            const float wf = Wfh[k * M_ + m];
            const float a0 = hl0[k], c0 = hr0[k];
            const float a1 = hl1[k], c1 = hr1[k];
            const float s0 = a0 + c0, s1 = a1 + c1;
            ai0 += s0 * wi; ao0 += s0 * wo; au0 += s0 * wu;
            ai1 += s1 * wi; ao1 += s1 * wo; au1 += s1 * wu;
            fl0 += a0 * wf; fr0 += c0 * wf;
            fl1 += a1 * wf; fr1 += c1 * wf;
        }
        const float bi = biouh[m], bo = biouh[m + 150], bu = biouh[m + 300], bf = bfh[m];
        {
            const float cl = LeafC[t0 * M_ + m], cr = LeafC[t1 * M_ + m];
            const float c = sgm(ai0 + bi) * tanhf(au0 + bu)
                          + sgm(fl0 + bf) * cl + sgm(fr0 + bf) * cr;
            const float h = sgm(ao0 + bo) * tanhf(c);
            HB[(2 * np) * M_ + m] = h; CB[(2 * np) * M_ + m] = c;
        }
        {
            const float cl = LeafC[t2 * M_ + m], cr = LeafC[t3 * M_ + m];
            const float c = sgm(ai1 + bi) * tanhf(au1 + bu)
                          + sgm(fl1 + bf) * cl + sgm(fr1 + bf) * cr;
            const float h = sgm(ao1 + bo) * tanhf(c);
            HB[(2 * np + 1) * M_ + m] = h; CB[(2 * np + 1) * M_ + m] = c;
        }
    }
    __syncthreads();

    // ---- levels 1..4: 32->16->8->4->2 (LDS ping-pong) ----
    float* Hcur = HB; float* Ccur = CB;
    float* Hnxt = HA; float* Cnxt = CA;
    for (int n_out = 16; n_out >= 2; n_out >>= 1) {
        const int NP = n_out / 2;
        for (int p = t; p < NP * M_; p += 256) {
            const int m  = p % M_;
            const int np = p / M_;
            const float* hl0 = Hcur + (4 * np + 0) * M_;
            const float* hr0 = Hcur + (4 * np + 1) * M_;
            const float* hl1 = Hcur + (4 * np + 2) * M_;
            const float* hr1 = Hcur + (4 * np + 3) * M_;
            float ai0 = 0, ao0 = 0, au0 = 0, fl0 = 0, fr0 = 0;
            float ai1 = 0, ao1 = 0, au1 = 0, fl1 = 0, fr1 = 0;
            for (int k = 0; k < M_; k++) {
                const float wi = Wiouh[k * 450 + m];
                const float wo = Wiouh[k * 450 + m + 150];
                const float wu = Wiouh[k * 450 + m + 300];
                const float wf = Wfh[k * M_ + m];
                const float a0 = hl0[k], c0 = hr0[k];
                const float a1 = hl1[k], c1 = hr1[k];
                const float s0 = a0 + c0, s1 = a1 + c1;
                ai0 += s0 * wi; ao0 += s0 * wo; au0 += s0 * wu;
                ai1 += s1 * wi; ao1 += s1 * wo; au1 += s1 * wu;
                fl0 += a0 * wf; fr0 += c0 * wf;
                fl1 += a1 * wf; fr1 += c1 * wf;
            }
            const float bi = biouh[m], bo = biouh[m + 150], bu = biouh[m + 300], bf = bfh[m];
            {
                const float cl = Ccur[(4 * np + 0) * M_ + m], cr = Ccur[(4 * np + 1) * M_ + m];
                const float c = sgm(ai0 + bi) * tanhf(au0 + bu)
                              + sgm(fl0 + bf) * cl + sgm(fr0 + bf) * cr;
                const float h = sgm(ao0 + bo) * tanhf(c);
                Hnxt[(2 * np) * M_ + m] = h; Cnxt[(2 * np) * M_ + m] = c;
            }
            {
                const float cl = Ccur[(4 * np + 2) * M_ + m], cr = Ccur[(4 * np + 3) * M_ + m];
                const float c = sgm(ai1 + bi) * tanhf(au1 + bu)
                              + sgm(fl1 + bf) * cl + sgm(fr1 + bf) * cr;
                const float h = sgm(ao1 + bo) * tanhf(c);
                Hnxt[(2 * np + 1) * M_ + m] = h; Cnxt[(2 * np + 1) * M_ + m] = c;
            }
        }
        __syncthreads();
        float* tmp;
        tmp = Hcur; Hcur = Hnxt; Hnxt = tmp;
        tmp = Ccur; Ccur = Cnxt; Cnxt = tmp;
    }

    // ---- final level: 2 -> 1, write root h to global ----
    for (int m = t; m < M_; m += 256) {
        const float* hl = Hcur;          // node 0
        const float* hr = Hcur + M_;     // node 1
        float ai = 0, ao = 0, au = 0, fl = 0, fr = 0;
        for (int k = 0; k < M_; k++) {
            const float wi = Wiouh[k * 450 + m];
            const float wo = Wiouh[k * 450 + m + 150];
            const float wu = Wiouh[k * 450 + m + 300];
            const float wf = Wfh[k * M_ + m];
            const float a = hl[k], c2 = hr[k];
            const float s = a + c2;
            ai += s * wi; ao += s * wo; au += s * wu;
            fl += a * wf; fr += c2 * wf;
        }
        const float cl = Ccur[m], cr = Ccur[M_ + m];
        const float c = sgm(ai + biouh[m]) * tanhf(au + biouh[m + 300])
                      + sgm(fl + bfh[m]) * cl + sgm(fr + bfh[m]) * cr;
        const float h = sgm(ao + biouh[m + 150]) * tanhf(c);
        RootH[b * M_ + m] = h;
    }
}

// ---------------------------------------------------------------------------
// K3: similarity head. One block (1 wave) per batch element.
// vec = [lh*rh, |lh-rh|]; mid = sigmoid(vec@Wh+bh); out = log_softmax(mid@Wp+bp)
// ---------------------------------------------------------------------------
__global__ __launch_bounds__(64) void head_kernel(
    const float* __restrict__ RootH,
    const float* __restrict__ Wh, const float* __restrict__ bh,
    const float* __restrict__ Wp, const float* __restrict__ bp,
    float* __restrict__ out)
{
    __shared__ float vec[2 * M_];
    __shared__ float mid[HID_];
    __shared__ float lg[NC_];
    __shared__ float lse;

    const int b = blockIdx.x;
    const int t = threadIdx.x;
    const float* lh = RootH + b * M_;
    const float* rh = RootH + (B_ + b) * M_;

    for (int i = t; i < M_; i += 64) {
        const float a = lh[i], c = rh[i];
        vec[i]      = a * c;
        vec[M_ + i] = fabsf(a - c);
    }
    __syncthreads();

    for (int j = t; j < HID_; j += 64) {
        float acc = bh[j];
        for (int k = 0; k < 2 * M_; k++) acc += vec[k] * Wh[k * HID_ + j];
        mid[j] = sgm(acc);
    }
    __syncthreads();

    if (t < NC_) {
        float acc = bp[t];
        for (int k = 0; k < HID_; k++) acc += mid[k] * Wp[k * NC_ + t];
        lg[t] = acc;
    }
    __syncthreads();

    if (t == 0) {
        float mx = lg[0];
        for (int i = 1; i < NC_; i++) mx = fmaxf(mx, lg[i]);
        float s = 0.0f;
        for (int i = 0; i < NC_; i++) s += expf(lg[i] - mx);
        lse = mx + logf(s);
    }
    __syncthreads();

    if (t < NC_) out[b * NC_ + t] = lg[t] - lse;
}

// ---------------------------------------------------------------------------
extern "C" void kernel_launch(void* const* d_in, const int* in_sizes, int n_in,
                              void* d_out, int out_size, void* d_ws, size_t ws_size,
                              hipStream_t stream)
{
    const int*   ltok  = (const int*)d_in[0];
    const int*   rtok  = (const int*)d_in[1];
    const float* emb   = (const float*)d_in[2];
    const float* Wioux = (const float*)d_in[3];
    const float* bioux = (const float*)d_in[4];
    const float* Wiouh = (const float*)d_in[5];
    const float* biouh = (const float*)d_in[6];
    // d_in[7] = Wfx, d_in[8] = bfx — unused by the reference computation
    const float* Wfh   = (const float*)d_in[9];
    const float* bfh   = (const float*)d_in[10];
    const float* Wh    = (const float*)d_in[11];
    const float* bh    = (const float*)d_in[12];
    const float* Wp    = (const float*)d_in[13];
    const float* bp    = (const float*)d_in[14];
    float* out = (float*)d_out;

    // Workspace layout (f32): LeafH[V*M] | LeafC[V*M] | RootH[2*B*M]  ~= 62.5 MB
    float* LeafH = (float*)d_ws;
    float* LeafC = LeafH + (size_t)V_ * M_;
    float* RootH = LeafC + (size_t)V_ * M_;

    hipLaunchKernelGGL(leaf_table_kernel, dim3((V_ + 31) / 32), dim3(256), 0, stream,
                       emb, Wioux, bioux, biouh, LeafH, LeafC);
    hipLaunchKernelGGL(tree_kernel, dim3(2 * B_), dim3(256), 0, stream,
                       ltok, rtok, LeafH, LeafC, Wiouh, biouh, Wfh, bfh, RootH);
    hipLaunchKernelGGL(head_kernel, dim3(B_), dim3(64), 0, stream,
                       RootH, Wh, bh, Wp, bp, out);
}

// Round 2
// 838.064 us; speedup vs baseline: 4.5036x; 4.5036x over previous
//
#include <hip/hip_runtime.h>
#include <hip/hip_bf16.h>
#include <math.h>

// Problem constants
constexpr int B_   = 2048;
constexpr int L_   = 64;
constexpr int V_   = 50000;
constexpr int IN_  = 300;
constexpr int M_   = 150;
constexpr int HID_ = 50;
constexpr int NC_  = 5;

// Padded dims
constexpr int KP_  = 160;   // padded K for tree-level GEMMs (state row stride, bf16)
constexpr int LVL_N  = 608; // 450 (iou) + 150 (f) padded to 38*16
constexpr int LVL_NT = 19;  // N-tiles per wave (38 total / 2 wave-halves)
constexpr int LVL_KC = 5;   // K chunks of 32 (150 -> 160)
constexpr int LEAF_N  = 480; // 450 padded to 30*16
constexpr int LEAF_NT = 15;  // per wave
constexpr int LEAF_KC = 10;  // 300 -> 320

typedef float f32x4  __attribute__((ext_vector_type(4)));
typedef short bf16x8 __attribute__((ext_vector_type(8)));
typedef short short4v __attribute__((ext_vector_type(4)));

__device__ __forceinline__ float sgm(float x) { return 1.0f / (1.0f + expf(-x)); }

__device__ __forceinline__ short f2bs(float f) {
    union { __hip_bfloat16 h; short s; } u; u.h = __float2bfloat16(f); return u.s;
}
__device__ __forceinline__ float bs2f(short s) {
    union { short s; __hip_bfloat16 h; } u; u.s = s; return __bfloat162float(u.h);
}

// ---------------------------------------------------------------------------
// K0: pack weights into k-chunked, n-major bf16 slabs.
// Bp[kc][n][kk] (kc<5, n<608, kk<32): k=kc*32+kk; n<450 -> Wiouh[k][n];
//   450<=n<600 -> Wfh[k][n-450]; else 0.  Bx[kc][n][kk] (kc<10, n<480): Wioux.
// ---------------------------------------------------------------------------
__global__ __launch_bounds__(256) void prep_kernel(
    const float* __restrict__ Wioux, const float* __restrict__ Wiouh,
    const float* __restrict__ Wfh, short* __restrict__ Bp, short* __restrict__ Bx)
{
    const int tid = blockIdx.x * blockDim.x + threadIdx.x;
    const int nthr = gridDim.x * blockDim.x;
    const int tot1 = LVL_KC * LVL_N * 32;     // 97280
    for (int idx = tid; idx < tot1; idx += nthr) {
        const int kc = idx / (LVL_N * 32);
        const int rem = idx % (LVL_N * 32);
        const int n = rem / 32, kk = rem % 32;
        const int k = kc * 32 + kk;
        float v = 0.0f;
        if (k < M_) {
            if (n < 450) v = Wiouh[k * 450 + n];
            else if (n < 600) v = Wfh[k * M_ + (n - 450)];
        }
        Bp[idx] = f2bs(v);
    }
    const int tot2 = LEAF_KC * LEAF_N * 32;   // 153600
    for (int idx = tid; idx < tot2; idx += nthr) {
        const int kc = idx / (LEAF_N * 32);
        const int rem = idx % (LEAF_N * 32);
        const int n = rem / 32, kk = rem % 32;
        const int k = kc * 32 + kk;
        float v = (k < IN_ && n < 450) ? Wioux[k * 450 + n] : 0.0f;
        Bx[idx] = f2bs(v);
    }
}

// ---------------------------------------------------------------------------
// K1: leaf tables via MFMA GEMM: emb[50000,300] @ Wioux[300,450] + biases
//   -> LeafH/LeafC bf16 [50000][160] (cols 150..159 zero).
// Block: 512 thr (8 waves), 64 rows, N=480. Wave w: M-tile w&3, N-half w>>2.
// ---------------------------------------------------------------------------
__global__ __launch_bounds__(512) void leaf_gemm(
    const float* __restrict__ emb, const short* __restrict__ Bx,
    const float* __restrict__ bioux, const float* __restrict__ biouh,
    short* __restrict__ LeafH, short* __restrict__ LeafC)
{
    __shared__ __align__(16) char smem[LEAF_N * 64 + 64 * 64];  // Bs 30720 + As 4096
    short* Bs = (short*)smem;
    short* As = (short*)(smem + LEAF_N * 64);
    float* Es = (float*)smem;                                   // [16][480] f32, reuses Bs

    const int t = threadIdx.x;
    const int row0 = blockIdx.x * 64;
    const int w = t >> 6, lane = t & 63;
    const int mt = w & 3, nt0 = (w >> 2) * LEAF_NT;
    const int lr = lane & 15, quad = lane >> 4;

    f32x4 acc[LEAF_NT];
    #pragma unroll
    for (int i = 0; i < LEAF_NT; i++) { acc[i][0] = 0; acc[i][1] = 0; acc[i][2] = 0; acc[i][3] = 0; }

    for (int kc = 0; kc < LEAF_KC; kc++) {
        // stage B chunk (contiguous slab)
        {
            const int4* bsrc = (const int4*)(Bx + (size_t)kc * LEAF_N * 32);
            int4* bdst = (int4*)Bs;
            for (int u = t; u < LEAF_N * 4; u += 512) bdst[u] = bsrc[u];
        }
        // stage A chunk: 64 rows x 32 k, f32 -> bf16
        {
            const int row = t >> 3, part = t & 7;
            const int v = row0 + row;
            const int k0 = kc * 32 + part * 4;
            float4 x = make_float4(0.f, 0.f, 0.f, 0.f);
            if (v < V_ && k0 < IN_) x = *(const float4*)&emb[(size_t)v * IN_ + k0];
            short4v s;
            s[0] = f2bs(x.x); s[1] = f2bs(x.y); s[2] = f2bs(x.z); s[3] = f2bs(x.w);
            *(short4v*)&As[row * 32 + part * 4] = s;
        }
        __syncthreads();
        bf16x8 a = *(const bf16x8*)&As[(mt * 16 + lr) * 32 + quad * 8];
        #pragma unroll
        for (int i = 0; i < LEAF_NT; i++) {
            bf16x8 b = *(const bf16x8*)&Bs[((nt0 + i) * 16 + lr) * 32 + quad * 8];
            acc[i] = __builtin_amdgcn_mfma_f32_16x16x32_bf16(a, b, acc[i], 0, 0, 0);
        }
        __syncthreads();
    }

    // epilogue: per M-tile, stage [16][480] f32, apply activations, store tables
    for (int mc = 0; mc < 4; mc++) {
        if (mt == mc) {
            #pragma unroll
            for (int i = 0; i < LEAF_NT; i++) {
                const int col = (nt0 + i) * 16 + lr;
                #pragma unroll
                for (int r = 0; r < 4; r++) Es[(quad * 4 + r) * LEAF_N + col] = acc[i][r];
            }
        }
        __syncthreads();
        for (int p = t; p < 16 * KP_; p += 512) {
            const int rl = p / KP_, n = p % KP_;
            const int v = row0 + mc * 16 + rl;
            if (v < V_) {
                if (n < M_) {
                    const float i_ = Es[rl * LEAF_N + n]       + bioux[n]       + biouh[n];
                    const float o_ = Es[rl * LEAF_N + n + 150] + bioux[n + 150] + biouh[n + 150];
                    const float u_ = Es[rl * LEAF_N + n + 300] + bioux[n + 300] + biouh[n + 300];
                    const float c = sgm(i_) * tanhf(u_);
                    const float h = sgm(o_) * tanhf(c);
                    LeafH[(size_t)v * KP_ + n] = f2bs(h);
                    LeafC[(size_t)v * KP_ + n] = f2bs(c);
                } else {
                    LeafH[(size_t)v * KP_ + n] = 0;
                    LeafC[(size_t)v * KP_ + n] = 0;
                }
            }
        }
        __syncthreads();
    }
}

// ---------------------------------------------------------------------------
// K2: one tree level. Unified GEMM over raw child rows:
//   G = Hchild[2R,150] @ [Wiouh | Wfh][150,600]
//   iou_r = G[2r,:450] + G[2r+1,:450] + biouh; f_{l,r} = G[2r/2r+1,450:600]+bfh
//   c = sgm(i)tanh(u) + sgm(fl)cl + sgm(fr)cr; h = sgm(o)tanh(c)
// Block: 512 thr, 64 child rows (-> 32 output rows), N=608.
// gather mode (level 0): child rows looked up from LeafH/LeafC via tokens.
// ---------------------------------------------------------------------------
__global__ __launch_bounds__(512) void level_gemm(
    const short* __restrict__ Hin, const short* __restrict__ Cin,
    const int* __restrict__ ltok, const int* __restrict__ rtok,
    const short* __restrict__ Bp,
    const float* __restrict__ biouh, const float* __restrict__ bfh,
    short* __restrict__ Hout, short* __restrict__ Cout)
{
    __shared__ __align__(16) char smem[LVL_N * 64 + 64 * 64];   // Bs 38912 + As 4096
    short* Bs = (short*)smem;
    short* As = (short*)(smem + LVL_N * 64);
    float* Es = (float*)smem;                                    // [16][608] f32, reuses Bs
    __shared__ int toks[64];

    const int t = threadIdx.x;
    const int row0 = blockIdx.x * 64;                            // first child row
    const bool gather = (ltok != nullptr);

    if (gather && t < 64) {
        const int g = row0 + t;
        toks[t] = (g < B_ * L_) ? ltok[g] : rtok[g - B_ * L_];
    }
    __syncthreads();

    const int w = t >> 6, lane = t & 63;
    const int mt = w & 3, nt0 = (w >> 2) * LVL_NT;
    const int lr = lane & 15, quad = lane >> 4;

    f32x4 acc[LVL_NT];
    #pragma unroll
    for (int i = 0; i < LVL_NT; i++) { acc[i][0] = 0; acc[i][1] = 0; acc[i][2] = 0; acc[i][3] = 0; }

    for (int kc = 0; kc < LVL_KC; kc++) {
        {
            const int4* bsrc = (const int4*)(Bp + (size_t)kc * LVL_N * 32);
            int4* bdst = (int4*)Bs;
            for (int u = t; u < LVL_N * 4; u += 512) bdst[u] = bsrc[u];
        }
        if (t < 256) {
            const int row = t >> 2, part = t & 3;
            const size_t srow = gather ? (size_t)toks[row] : (size_t)(row0 + row);
            const short* src = Hin + srow * KP_ + kc * 32 + part * 8;
            *(int4*)&As[row * 32 + part * 8] = *(const int4*)src;
        }
        __syncthreads();
        bf16x8 a = *(const bf16x8*)&As[(mt * 16 + lr) * 32 + quad * 8];
        #pragma unroll
        for (int i = 0; i < LVL_NT; i++) {
            bf16x8 b = *(const bf16x8*)&Bs[((nt0 + i) * 16 + lr) * 32 + quad * 8];
            acc[i] = __builtin_amdgcn_mfma_f32_16x16x32_bf16(a, b, acc[i], 0, 0, 0);
        }
        __syncthreads();
    }

    for (int mc = 0; mc < 4; mc++) {
        if (mt == mc) {
            #pragma unroll
            for (int i = 0; i < LVL_NT; i++) {
                const int col = (nt0 + i) * 16 + lr;
                #pragma unroll
                for (int r = 0; r < 4; r++) Es[(quad * 4 + r) * LVL_N + col] = acc[i][r];
            }
        }
        __syncthreads();
        for (int p = t; p < 8 * KP_; p += 512) {
            const int rl = p / KP_, n = p % KP_;
            const int r_out = blockIdx.x * 32 + mc * 8 + rl;
            if (n < M_) {
                const int e0 = (2 * rl) * LVL_N, e1 = (2 * rl + 1) * LVL_N;
                const float i_ = Es[e0 + n]       + Es[e1 + n]       + biouh[n];
                const float o_ = Es[e0 + n + 150] + Es[e1 + n + 150] + biouh[n + 150];
                const float u_ = Es[e0 + n + 300] + Es[e1 + n + 300] + biouh[n + 300];
                const float fl = Es[e0 + n + 450] + bfh[n];
                const float fr = Es[e1 + n + 450] + bfh[n];
                const int lc0 = mc * 16 + 2 * rl;                // local child idx
                float cl, cr;
                if (gather) {
                    cl = bs2f(Cin[(size_t)toks[lc0]     * KP_ + n]);
                    cr = bs2f(Cin[(size_t)toks[lc0 + 1] * KP_ + n]);
                } else {
                    cl = bs2f(Cin[(size_t)(row0 + lc0)     * KP_ + n]);
                    cr = bs2f(Cin[(size_t)(row0 + lc0 + 1) * KP_ + n]);
                }
                const float c = sgm(i_) * tanhf(u_) + sgm(fl) * cl + sgm(fr) * cr;
                const float h = sgm(o_) * tanhf(c);
                Hout[(size_t)r_out * KP_ + n] = f2bs(h);
                Cout[(size_t)r_out * KP_ + n] = f2bs(c);
            } else {
                Hout[(size_t)r_out * KP_ + n] = 0;
                Cout[(size_t)r_out * KP_ + n] = 0;
            }
        }
        __syncthreads();
    }
}

// ---------------------------------------------------------------------------
// K3: similarity head (one wave per pair). Roots are bf16 rows, stride 160.
// ---------------------------------------------------------------------------
__global__ __launch_bounds__(64) void head_kernel(
    const short* __restrict__ RootH,
    const float* __restrict__ Wh, const float* __restrict__ bh,
    const float* __restrict__ Wp, const float* __restrict__ bp,
    float* __restrict__ out)
{
    __shared__ float vec[2 * M_];
    __shared__ float mid[HID_];
    __shared__ float lg[NC_];
    __shared__ float lse;

    const int b = blockIdx.x;
    const int t = threadIdx.x;
    const short* lh = RootH + (size_t)b * KP_;
    const short* rh = RootH + (size_t)(B_ + b) * KP_;

    for (int i = t; i < M_; i += 64) {
        const float a = bs2f(lh[i]), c = bs2f(rh[i]);
        vec[i]      = a * c;
        vec[M_ + i] = fabsf(a - c);
    }
    __syncthreads();

    for (int j = t; j < HID_; j += 64) {
        float acc = bh[j];
        for (int k = 0; k < 2 * M_; k++) acc += vec[k] * Wh[k * HID_ + j];
        mid[j] = sgm(acc);
    }
    __syncthreads();

    if (t < NC_) {
        float acc = bp[t];
        for (int k = 0; k < HID_; k++) acc += mid[k] * Wp[k * NC_ + t];
        lg[t] = acc;
    }
    __syncthreads();

    if (t == 0) {
        float mx = lg[0];
        for (int i = 1; i < NC_; i++) mx = fmaxf(mx, lg[i]);
        float s = 0.0f;
        for (int i = 0; i < NC_; i++) s += expf(lg[i] - mx);
        lse = mx + logf(s);
    }
    __syncthreads();

    if (t < NC_) out[b * NC_ + t] = lg[t] - lse;
}

// ---------------------------------------------------------------------------
extern "C" void kernel_launch(void* const* d_in, const int* in_sizes, int n_in,
                              void* d_out, int out_size, void* d_ws, size_t ws_size,
                              hipStream_t stream)
{
    const int*   ltok  = (const int*)d_in[0];
    const int*   rtok  = (const int*)d_in[1];
    const float* emb   = (const float*)d_in[2];
    const float* Wioux = (const float*)d_in[3];
    const float* bioux = (const float*)d_in[4];
    const float* Wiouh = (const float*)d_in[5];
    const float* biouh = (const float*)d_in[6];
    const float* Wfh   = (const float*)d_in[9];
    const float* bfh   = (const float*)d_in[10];
    const float* Wh    = (const float*)d_in[11];
    const float* bh    = (const float*)d_in[12];
    const float* Wp    = (const float*)d_in[13];
    const float* bp    = (const float*)d_in[14];
    float* out = (float*)d_out;

    // Workspace carve-up (bytes, 256-aligned). Total ~158.4 MB.
    char* ws = (char*)d_ws;
    size_t off = 0;
    auto carve = [&](size_t bytes) { char* p = ws + off; off += (bytes + 255) & ~(size_t)255; return p; };
    short* Bp    = (short*)carve((size_t)LVL_KC * LVL_N * 32 * 2);     // 194,560
    short* Bx    = (short*)carve((size_t)LEAF_KC * LEAF_N * 32 * 2);   // 307,200
    short* LeafH = (short*)carve((size_t)V_ * KP_ * 2);                // 16 MB
    short* LeafC = (short*)carve((size_t)V_ * KP_ * 2);                // 16 MB
    short* HA    = (short*)carve((size_t)131072 * KP_ * 2);            // 41.9 MB
    short* CA    = (short*)carve((size_t)131072 * KP_ * 2);            // 41.9 MB
    short* HB    = (short*)carve((size_t)65536 * KP_ * 2);             // 21.0 MB
    short* CB    = (short*)carve((size_t)65536 * KP_ * 2);             // 21.0 MB

    hipLaunchKernelGGL(prep_kernel, dim3(128), dim3(256), 0, stream, Wioux, Wiouh, Wfh, Bp, Bx);
    hipLaunchKernelGGL(leaf_gemm, dim3((V_ + 63) / 64), dim3(512), 0, stream,
                       emb, Bx, bioux, biouh, LeafH, LeafC);
    // level 0: 262144 child rows (gathered from tables) -> 131072 nodes
    hipLaunchKernelGGL(level_gemm, dim3(4096), dim3(512), 0, stream,
                       LeafH, LeafC, ltok, rtok, Bp, biouh, bfh, HA, CA);
    // levels 1..5
    hipLaunchKernelGGL(level_gemm, dim3(2048), dim3(512), 0, stream,
                       HA, CA, (const int*)nullptr, (const int*)nullptr, Bp, biouh, bfh, HB, CB);
    hipLaunchKernelGGL(level_gemm, dim3(1024), dim3(512), 0, stream,
                       HB, CB, (const int*)nullptr, (const int*)nullptr, Bp, biouh, bfh, HA, CA);
    hipLaunchKernelGGL(level_gemm, dim3(512), dim3(512), 0, stream,
                       HA, CA, (const int*)nullptr, (const int*)nullptr, Bp, biouh, bfh, HB, CB);
    hipLaunchKernelGGL(level_gemm, dim3(256), dim3(512), 0, stream,
                       HB, CB, (const int*)nullptr, (const int*)nullptr, Bp, biouh, bfh, HA, CA);
    hipLaunchKernelGGL(level_gemm, dim3(128), dim3(512), 0, stream,
                       HA, CA, (const int*)nullptr, (const int*)nullptr, Bp, biouh, bfh, HB, CB);
    // roots: HB rows [0..2047]=left, [2048..4095]=right
    hipLaunchKernelGGL(head_kernel, dim3(B_), dim3(64), 0, stream, HB, Wh, bh, Wp, bp, out);
}

// Round 3
// 575.400 us; speedup vs baseline: 6.5595x; 1.4565x over previous
//
#include <hip/hip_runtime.h>
#include <hip/hip_bf16.h>
#include <math.h>

// Problem constants
constexpr int B_   = 2048;
constexpr int L_   = 64;
constexpr int V_   = 50000;
constexpr int IN_  = 300;
constexpr int M_   = 150;
constexpr int HID_ = 50;
constexpr int NC_  = 5;

// Padded dims
constexpr int KP_  = 160;    // state row stride (bf16)
constexpr int EN_  = 608;    // LeafE row stride: 450 G + 150 FC + 8 pad
constexpr int LVL_N  = 608;  // 450 iou + 150 f, padded
constexpr int LVL_NT = 19;
constexpr int LVL_KC = 5;    // K chunks of 32 (150 -> 160)
constexpr int LVL_CH = LVL_N * 32;        // shorts per chunk (19456)
constexpr int LVL_QS = LVL_N * 8;         // shorts per quad-segment (4864)
constexpr int LEAF_N  = 480;
constexpr int LEAF_NT = 15;
constexpr int LEAF_KC = 10;  // 300 -> 320
constexpr int LEAF_CH = LEAF_N * 32;      // 15360
constexpr int LEAF_QS = LEAF_N * 8;       // 3840

typedef float f32x4  __attribute__((ext_vector_type(4)));
typedef short bf16x8 __attribute__((ext_vector_type(8)));
typedef short short4v __attribute__((ext_vector_type(4)));

__device__ __forceinline__ float rcp_f(float x) { return __builtin_amdgcn_rcpf(x); }
__device__ __forceinline__ float sgm(float x)   { return rcp_f(1.0f + __expf(-x)); }
__device__ __forceinline__ float tanh_f(float x){ return 1.0f - 2.0f * rcp_f(1.0f + __expf(2.0f * x)); }

__device__ __forceinline__ short f2bs(float f) {
    union { __hip_bfloat16 h; short s; } u; u.h = __float2bfloat16(f); return u.s;
}
__device__ __forceinline__ float bs2f(short s) {
    union { short s; __hip_bfloat16 h; } u; u.s = s; return __bfloat162float(u.h);
}

// async global->LDS 16B: per-lane gptr, wave-uniform lds base (+lane*16 in HW)
__device__ __forceinline__ void gl_lds16(const short* g, short* l) {
    __builtin_amdgcn_global_load_lds(
        (const __attribute__((address_space(1))) unsigned int*)g,
        (__attribute__((address_space(3))) unsigned int*)l, 16, 0, 0);
}

// ---------------------------------------------------------------------------
// K0: pack weights, k-chunked + quad-interleaved so LDS fragment reads are
// 16B-stride across lanes (conflict-free) while staging stays linear.
// Bp[kc][q][n][8]: k=kc*32+q*8+j; n<450->Wiouh[k][n]; 450<=n<600->Wfh[k][n-450]
// Bx[kc][q][n][8]: Wioux[k][n] (k<300, n<450)
// ---------------------------------------------------------------------------
__global__ __launch_bounds__(256) void prep_kernel(
    const float* __restrict__ Wioux, const float* __restrict__ Wiouh,
    const float* __restrict__ Wfh, short* __restrict__ Bp, short* __restrict__ Bx)
{
    const int tid = blockIdx.x * blockDim.x + threadIdx.x;
    const int nthr = gridDim.x * blockDim.x;
    const int tot1 = LVL_KC * LVL_CH;
    for (int idx = tid; idx < tot1; idx += nthr) {
        const int kc = idx / LVL_CH;
        int rem = idx % LVL_CH;
        const int q = rem / LVL_QS; rem %= LVL_QS;
        const int n = rem / 8, j = rem % 8;
        const int k = kc * 32 + q * 8 + j;
        float v = 0.0f;
        if (k < M_) {
            if (n < 450) v = Wiouh[k * 450 + n];
            else if (n < 600) v = Wfh[k * M_ + (n - 450)];
        }
        Bp[idx] = f2bs(v);
    }
    const int tot2 = LEAF_KC * LEAF_CH;
    for (int idx = tid; idx < tot2; idx += nthr) {
        const int kc = idx / LEAF_CH;
        int rem = idx % LEAF_CH;
        const int q = rem / LEAF_QS; rem %= LEAF_QS;
        const int n = rem / 8, j = rem % 8;
        const int k = kc * 32 + q * 8 + j;
        float v = (k < IN_ && n < 450) ? Wioux[k * 450 + n] : 0.0f;
        Bx[idx] = f2bs(v);
    }
}

// ---------------------------------------------------------------------------
// K1: leaf tables: emb[V,300] @ Wioux[300,450] -> LeafH/LeafC bf16 [V,160]
// ---------------------------------------------------------------------------
__global__ __launch_bounds__(512) void leaf_gemm(
    const float* __restrict__ emb, const short* __restrict__ Bx,
    const float* __restrict__ bioux, const float* __restrict__ biouh,
    short* __restrict__ LeafH, short* __restrict__ LeafC)
{
    __shared__ __align__(16) char smem[LEAF_CH * 2 + 64 * 64];  // Bs 30720B + As 4096B
    short* Bs = (short*)smem;
    short* As = (short*)(smem + LEAF_CH * 2);
    float* Es = (float*)smem;                                   // [16][480] f32

    const int t = threadIdx.x;
    const int row0 = blockIdx.x * 64;
    const int w = t >> 6, lane = t & 63;
    const int mt = w & 3, nt0 = (w >> 2) * LEAF_NT;
    const int lr = lane & 15, quad = lane >> 4;

    f32x4 acc[LEAF_NT];
    #pragma unroll
    for (int i = 0; i < LEAF_NT; i++) { acc[i][0] = 0; acc[i][1] = 0; acc[i][2] = 0; acc[i][3] = 0; }

    // A staging indices (f32 -> bf16 via VGPR)
    const int arow = t >> 3, apart = t & 7;
    const int av = row0 + arow;
    const int aq = apart >> 1, aj = (apart & 1) * 4;

    for (int kc = 0; kc < LEAF_KC; kc++) {
        const short* bsrc = Bx + (size_t)kc * LEAF_CH;
        #pragma unroll
        for (int i = 0; i < 3; i++)
            gl_lds16(bsrc + (i * 512 + t) * 8, Bs + (i * 512 + (t & ~63)) * 8);
        if (t < 384)
            gl_lds16(bsrc + (1536 + t) * 8, Bs + (1536 + (t & ~63)) * 8);
        {
            const int k0 = kc * 32 + apart * 4;
            float4 x = make_float4(0.f, 0.f, 0.f, 0.f);
            if (av < V_ && k0 < IN_) x = *(const float4*)&emb[(size_t)av * IN_ + k0];
            short4v s;
            s[0] = f2bs(x.x); s[1] = f2bs(x.y); s[2] = f2bs(x.z); s[3] = f2bs(x.w);
            *(short4v*)&As[aq * 512 + arow * 8 + aj] = s;
        }
        __syncthreads();
        bf16x8 a = *(const bf16x8*)&As[quad * 512 + (mt * 16 + lr) * 8];
        #pragma unroll
        for (int i = 0; i < LEAF_NT; i++) {
            bf16x8 b = *(const bf16x8*)&Bs[quad * LEAF_QS + ((nt0 + i) * 16 + lr) * 8];
            acc[i] = __builtin_amdgcn_mfma_f32_16x16x32_bf16(a, b, acc[i], 0, 0, 0);
        }
        __syncthreads();
    }

    for (int mc = 0; mc < 4; mc++) {
        if (mt == mc) {
            #pragma unroll
            for (int i = 0; i < LEAF_NT; i++) {
                const int col = (nt0 + i) * 16 + lr;
                #pragma unroll
                for (int r = 0; r < 4; r++) Es[(quad * 4 + r) * LEAF_N + col] = acc[i][r];
            }
        }
        __syncthreads();
        for (int p = t; p < 16 * KP_; p += 512) {
            const int rl = p / KP_, n = p % KP_;
            const int v = row0 + mc * 16 + rl;
            if (v < V_) {
                if (n < M_) {
                    const float i_ = Es[rl * LEAF_N + n]       + bioux[n]       + biouh[n];
                    const float o_ = Es[rl * LEAF_N + n + 150] + bioux[n + 150] + biouh[n + 150];
                    const float u_ = Es[rl * LEAF_N + n + 300] + bioux[n + 300] + biouh[n + 300];
                    const float c = sgm(i_) * tanh_f(u_);
                    const float h = sgm(o_) * tanh_f(c);
                    LeafH[(size_t)v * KP_ + n] = f2bs(h);
                    LeafC[(size_t)v * KP_ + n] = f2bs(c);
                } else {
                    LeafH[(size_t)v * KP_ + n] = 0;
                    LeafC[(size_t)v * KP_ + n] = 0;
                }
            }
        }
        __syncthreads();
    }
}

// ---------------------------------------------------------------------------
// K2: per-vocab level-0 tables: LeafH[V,160] @ [Wiouh|Wfh] -> LeafE[V,608]
//   cols 0..449:  G  = raw iou contribution (bias added later)
//   cols 450..599: FC = sigmoid(F + bfh) * LeafC   (whole forget-product!)
// ---------------------------------------------------------------------------
__global__ __launch_bounds__(512) void leafGF_gemm(
    const short* __restrict__ LeafH, const short* __restrict__ LeafC,
    const short* __restrict__ Bp, const float* __restrict__ bfh,
    short* __restrict__ LeafE)
{
    __shared__ __align__(16) char smem[LVL_CH * 2 + 64 * 64];   // Bs 38912B + As 4096B
    short* Bs = (short*)smem;
    short* As = (short*)(smem + LVL_CH * 2);
    float* Es = (float*)smem;                                    // [16][608] f32

    const int t = threadIdx.x;
    const int row0 = blockIdx.x * 64;
    const int w = t >> 6, lane = t & 63;
    const int mt = w & 3, nt0 = (w >> 2) * LVL_NT;
    const int lr = lane & 15, quad = lane >> 4;

    f32x4 acc[LVL_NT];
    #pragma unroll
    for (int i = 0; i < LVL_NT; i++) { acc[i][0] = 0; acc[i][1] = 0; acc[i][2] = 0; acc[i][3] = 0; }

    const int arow = t & 63, apart = t >> 6;   // t<256 stages A
    const size_t srow = (size_t)((row0 + arow < V_) ? (row0 + arow) : 0);
    const short* asrc = LeafH + srow * KP_ + apart * 8;

    for (int kc = 0; kc < LVL_KC; kc++) {
        const short* bsrc = Bp + (size_t)kc * LVL_CH;
        #pragma unroll
        for (int i = 0; i < 4; i++)
            gl_lds16(bsrc + (i * 512 + t) * 8, Bs + (i * 512 + (t & ~63)) * 8);
        if (t < 384)
            gl_lds16(bsrc + (2048 + t) * 8, Bs + (2048 + (t & ~63)) * 8);
        if (t < 256)
            gl_lds16(asrc + kc * 32, As + (t & ~63) * 8);
        __syncthreads();
        bf16x8 a = *(const bf16x8*)&As[quad * 512 + (mt * 16 + lr) * 8];
        #pragma unroll
        for (int i = 0; i < LVL_NT; i++) {
            bf16x8 b = *(const bf16x8*)&Bs[quad * LVL_QS + ((nt0 + i) * 16 + lr) * 8];
            acc[i] = __builtin_amdgcn_mfma_f32_16x16x32_bf16(a, b, acc[i], 0, 0, 0);
        }
        __syncthreads();
    }

    for (int mc = 0; mc < 4; mc++) {
        if (mt == mc) {
            #pragma unroll
            for (int i = 0; i < LVL_NT; i++) {
                const int col = (nt0 + i) * 16 + lr;
                #pragma unroll
                for (int r = 0; r < 4; r++) Es[(quad * 4 + r) * LVL_N + col] = acc[i][r];
            }
        }
        __syncthreads();
        for (int p = t; p < 16 * EN_; p += 512) {
            const int rl = p / EN_, n = p % EN_;
            const int v = row0 + mc * 16 + rl;
            if (v < V_) {
                short outv = 0;
                if (n < 450) {
                    outv = f2bs(Es[rl * LVL_N + n]);
                } else if (n < 600) {
                    const int m = n - 450;
                    const float f = sgm(Es[rl * LVL_N + n] + bfh[m]);
                    outv = f2bs(f * bs2f(LeafC[(size_t)v * KP_ + m]));
                }
                LeafE[(size_t)v * EN_ + n] = outv;
            }
        }
        __syncthreads();
    }
}

// ---------------------------------------------------------------------------
// K3: level 0 as pure gather+elementwise (token-determined tables).
// One wave per node; 131072 nodes.
// ---------------------------------------------------------------------------
__global__ __launch_bounds__(256) void level0_kernel(
    const int* __restrict__ ltok, const int* __restrict__ rtok,
    const short* __restrict__ LeafE, const float* __restrict__ biouh,
    short* __restrict__ Hout, short* __restrict__ Cout)
{
    const int w = threadIdx.x >> 6, lane = threadIdx.x & 63;
    const int nd = blockIdx.x * 4 + w;
    const int g0 = 2 * nd, g1 = g0 + 1;
    const int half = B_ * L_;
    const int tl = (g0 < half) ? ltok[g0] : rtok[g0 - half];
    const int tr = (g1 < half) ? ltok[g1] : rtok[g1 - half];
    const short* el = LeafE + (size_t)tl * EN_;
    const short* er = LeafE + (size_t)tr * EN_;
    for (int m = lane; m < KP_; m += 64) {
        float h = 0.0f, c = 0.0f;
        if (m < M_) {
            const float i_ = bs2f(el[m])       + bs2f(er[m])       + biouh[m];
            const float o_ = bs2f(el[m + 150]) + bs2f(er[m + 150]) + biouh[m + 150];
            const float u_ = bs2f(el[m + 300]) + bs2f(er[m + 300]) + biouh[m + 300];
            const float fc = bs2f(el[m + 450]) + bs2f(er[m + 450]);
            c = sgm(i_) * tanh_f(u_) + fc;
            h = sgm(o_) * tanh_f(c);
        }
        Hout[(size_t)nd * KP_ + m] = f2bs(h);
        Cout[(size_t)nd * KP_ + m] = f2bs(c);
    }
}

// ---------------------------------------------------------------------------
// K4: one internal tree level (levels 1..5), unified GEMM over child rows.
// ---------------------------------------------------------------------------
__global__ __launch_bounds__(512) void level_gemm(
    const short* __restrict__ Hin, const short* __restrict__ Cin,
    const short* __restrict__ Bp,
    const float* __restrict__ biouh, const float* __restrict__ bfh,
    short* __restrict__ Hout, short* __restrict__ Cout)
{
    __shared__ __align__(16) char smem[LVL_CH * 2 + 64 * 64];
    short* Bs = (short*)smem;
    short* As = (short*)(smem + LVL_CH * 2);
    float* Es = (float*)smem;

    const int t = threadIdx.x;
    const int row0 = blockIdx.x * 64;
    const int w = t >> 6, lane = t & 63;
    const int mt = w & 3, nt0 = (w >> 2) * LVL_NT;
    const int lr = lane & 15, quad = lane >> 4;

    f32x4 acc[LVL_NT];
    #pragma unroll
    for (int i = 0; i < LVL_NT; i++) { acc[i][0] = 0; acc[i][1] = 0; acc[i][2] = 0; acc[i][3] = 0; }

    const int arow = t & 63, apart = t >> 6;   // t<256 stages A
    const short* asrc = Hin + (size_t)(row0 + arow) * KP_ + apart * 8;

    for (int kc = 0; kc < LVL_KC; kc++) {
        const short* bsrc = Bp + (size_t)kc * LVL_CH;
        #pragma unroll
        for (int i = 0; i < 4; i++)
            gl_lds16(bsrc + (i * 512 + t) * 8, Bs + (i * 512 + (t & ~63)) * 8);
        if (t < 384)
            gl_lds16(bsrc + (2048 + t) * 8, Bs + (2048 + (t & ~63)) * 8);
        if (t < 256)
            gl_lds16(asrc + kc * 32, As + (t & ~63) * 8);
        __syncthreads();
        bf16x8 a = *(const bf16x8*)&As[quad * 512 + (mt * 16 + lr) * 8];
        #pragma unroll
        for (int i = 0; i < LVL_NT; i++) {
            bf16x8 b = *(const bf16x8*)&Bs[quad * LVL_QS + ((nt0 + i) * 16 + lr) * 8];
            acc[i] = __builtin_amdgcn_mfma_f32_16x16x32_bf16(a, b, acc[i], 0, 0, 0);
        }
        __syncthreads();
    }

    for (int mc = 0; mc < 4; mc++) {
        if (mt == mc) {
            #pragma unroll
            for (int i = 0; i < LVL_NT; i++) {
                const int col = (nt0 + i) * 16 + lr;
                #pragma unroll
                for (int r = 0; r < 4; r++) Es[(quad * 4 + r) * LVL_N + col] = acc[i][r];
            }
        }
        __syncthreads();
        for (int p = t; p < 8 * KP_; p += 512) {
            const int rl = p / KP_, n = p % KP_;
            const int r_out = blockIdx.x * 32 + mc * 8 + rl;
            if (n < M_) {
                const int e0 = (2 * rl) * LVL_N, e1 = (2 * rl + 1) * LVL_N;
                const float i_ = Es[e0 + n]       + Es[e1 + n]       + biouh[n];
                const float o_ = Es[e0 + n + 150] + Es[e1 + n + 150] + biouh[n + 150];
                const float u_ = Es[e0 + n + 300] + Es[e1 + n + 300] + biouh[n + 300];
                const float fl = Es[e0 + n + 450] + bfh[n];
                const float fr = Es[e1 + n + 450] + bfh[n];
                const int lc0 = mc * 16 + 2 * rl;
                const float cl = bs2f(Cin[(size_t)(row0 + lc0)     * KP_ + n]);
                const float cr = bs2f(Cin[(size_t)(row0 + lc0 + 1) * KP_ + n]);
                const float c = sgm(i_) * tanh_f(u_) + sgm(fl) * cl + sgm(fr) * cr;
                const float h = sgm(o_) * tanh_f(c);
                Hout[(size_t)r_out * KP_ + n] = f2bs(h);
                Cout[(size_t)r_out * KP_ + n] = f2bs(c);
            } else {
                Hout[(size_t)r_out * KP_ + n] = 0;
                Cout[(size_t)r_out * KP_ + n] = 0;
            }
        }
        __syncthreads();
    }
}

// ---------------------------------------------------------------------------
// K5: similarity head (one wave per pair).
// ---------------------------------------------------------------------------
__global__ __launch_bounds__(64) void head_kernel(
    const short* __restrict__ RootH,
    const float* __restrict__ Wh, const float* __restrict__ bh,
    const float* __restrict__ Wp, const float* __restrict__ bp,
    float* __restrict__ out)
{
    __shared__ float vec[2 * M_];
    __shared__ float mid[HID_];
    __shared__ float lg[NC_];
    __shared__ float lse;

    const int b = blockIdx.x;
    const int t = threadIdx.x;
    const short* lh = RootH + (size_t)b * KP_;
    const short* rh = RootH + (size_t)(B_ + b) * KP_;

    for (int i = t; i < M_; i += 64) {
        const float a = bs2f(lh[i]), c = bs2f(rh[i]);
        vec[i]      = a * c;
        vec[M_ + i] = fabsf(a - c);
    }
    __syncthreads();

    for (int j = t; j < HID_; j += 64) {
        float acc = bh[j];
        for (int k = 0; k < 2 * M_; k++) acc += vec[k] * Wh[k * HID_ + j];
        mid[j] = sgm(acc);
    }
    __syncthreads();

    if (t < NC_) {
        float acc = bp[t];
        for (int k = 0; k < HID_; k++) acc += mid[k] * Wp[k * NC_ + t];
        lg[t] = acc;
    }
    __syncthreads();

    if (t == 0) {
        float mx = lg[0];
        for (int i = 1; i < NC_; i++) mx = fmaxf(mx, lg[i]);
        float s = 0.0f;
        for (int i = 0; i < NC_; i++) s += expf(lg[i] - mx);
        lse = mx + logf(s);
    }
    __syncthreads();

    if (t < NC_) out[b * NC_ + t] = lg[t] - lse;
}

// ---------------------------------------------------------------------------
extern "C" void kernel_launch(void* const* d_in, const int* in_sizes, int n_in,
                              void* d_out, int out_size, void* d_ws, size_t ws_size,
                              hipStream_t stream)
{
    const int*   ltok  = (const int*)d_in[0];
    const int*   rtok  = (const int*)d_in[1];
    const float* emb   = (const float*)d_in[2];
    const float* Wioux = (const float*)d_in[3];
    const float* bioux = (const float*)d_in[4];
    const float* Wiouh = (const float*)d_in[5];
    const float* biouh = (const float*)d_in[6];
    const float* Wfh   = (const float*)d_in[9];
    const float* bfh   = (const float*)d_in[10];
    const float* Wh    = (const float*)d_in[11];
    const float* bh    = (const float*)d_in[12];
    const float* Wp    = (const float*)d_in[13];
    const float* bp    = (const float*)d_in[14];
    float* out = (float*)d_out;

    // Workspace carve-up (~220 MB)
    char* ws = (char*)d_ws;
    size_t off = 0;
    auto carve = [&](size_t bytes) { char* p = ws + off; off += (bytes + 255) & ~(size_t)255; return p; };
    short* Bp    = (short*)carve((size_t)LVL_KC * LVL_CH * 2);
    short* Bx    = (short*)carve((size_t)LEAF_KC * LEAF_CH * 2);
    short* LeafH = (short*)carve((size_t)V_ * KP_ * 2);        // 16 MB
    short* LeafC = (short*)carve((size_t)V_ * KP_ * 2);        // 16 MB
    short* LeafE = (short*)carve((size_t)V_ * EN_ * 2);        // 60.8 MB
    short* HA    = (short*)carve((size_t)131072 * KP_ * 2);    // 42 MB
    short* CA    = (short*)carve((size_t)131072 * KP_ * 2);    // 42 MB
    short* HB    = (short*)carve((size_t)65536 * KP_ * 2);     // 21 MB
    short* CB    = (short*)carve((size_t)65536 * KP_ * 2);     // 21 MB

    hipLaunchKernelGGL(prep_kernel, dim3(128), dim3(256), 0, stream, Wioux, Wiouh, Wfh, Bp, Bx);
    hipLaunchKernelGGL(leaf_gemm, dim3((V_ + 63) / 64), dim3(512), 0, stream,
                       emb, Bx, bioux, biouh, LeafH, LeafC);
    hipLaunchKernelGGL(leafGF_gemm, dim3((V_ + 63) / 64), dim3(512), 0, stream,
                       LeafH, LeafC, Bp, bfh, LeafE);
    // level 0: 131072 nodes, pure gather/elementwise
    hipLaunchKernelGGL(level0_kernel, dim3(32768), dim3(256), 0, stream,
                       ltok, rtok, LeafE, biouh, HA, CA);
    // levels 1..5: 131072 -> 65536 -> 32768 -> 16384 -> 8192 -> 4096 rows
    hipLaunchKernelGGL(level_gemm, dim3(2048), dim3(512), 0, stream,
                       HA, CA, Bp, biouh, bfh, HB, CB);
    hipLaunchKernelGGL(level_gemm, dim3(1024), dim3(512), 0, stream,
                       HB, CB, Bp, biouh, bfh, HA, CA);
    hipLaunchKernelGGL(level_gemm, dim3(512), dim3(512), 0, stream,
                       HA, CA, Bp, biouh, bfh, HB, CB);
    hipLaunchKernelGGL(level_gemm, dim3(256), dim3(512), 0, stream,
                       HB, CB, Bp, biouh, bfh, HA, CA);
    hipLaunchKernelGGL(level_gemm, dim3(128), dim3(512), 0, stream,
                       HA, CA, Bp, biouh, bfh, HB, CB);
    hipLaunchKernelGGL(head_kernel, dim3(B_), dim3(64), 0, stream, HB, Wh, bh, Wp, bp, out);
}

// Round 5
// 537.173 us; speedup vs baseline: 7.0263x; 1.0712x over previous
//
#include <hip/hip_runtime.h>
#include <hip/hip_bf16.h>
#include <math.h>

// Problem constants
constexpr int B_   = 2048;
constexpr int L_   = 64;
constexpr int V_   = 50000;
constexpr int IN_  = 300;
constexpr int M_   = 150;
constexpr int HID_ = 50;
constexpr int NC_  = 5;

// Padded dims
constexpr int KP_  = 160;            // state row stride (bf16)
constexpr int GN_  = 608;            // gate-interleaved N: col = 4m+g, m<152
constexpr int GNT_ = 19;             // N-tiles per wave-half (38 total)
constexpr int GKC_ = 5;              // K chunks of 32 (150 -> 160)
constexpr int GCH_ = GN_ * 32;       // shorts per B chunk (19456)
constexpr int GQS_ = GN_ * 8;        // shorts per quad segment (4864)
constexpr int LEAF_N  = 480;
constexpr int LEAF_NT = 15;
constexpr int LEAF_KC = 10;          // 300 -> 320
constexpr int LEAF_CH = LEAF_N * 32; // 15360
constexpr int LEAF_QS = LEAF_N * 8;  // 3840

typedef float f32x4  __attribute__((ext_vector_type(4)));
typedef short bf16x8 __attribute__((ext_vector_type(8)));
typedef short short4v __attribute__((ext_vector_type(4)));

__device__ __forceinline__ float rcp_f(float x) { return __builtin_amdgcn_rcpf(x); }
__device__ __forceinline__ float sgm(float x)   { return rcp_f(1.0f + __expf(-x)); }
__device__ __forceinline__ float tanh_f(float x){ return 1.0f - 2.0f * rcp_f(1.0f + __expf(2.0f * x)); }

__device__ __forceinline__ short f2bs(float f) {
    union { __hip_bfloat16 h; short s; } u; u.h = __float2bfloat16(f); return u.s;
}
__device__ __forceinline__ float bs2f(short s) {
    union { short s; __hip_bfloat16 h; } u; u.s = s; return __bfloat162float(u.h);
}

__device__ __forceinline__ void gl_lds16(const short* g, short* l) {
    __builtin_amdgcn_global_load_lds(
        (const __attribute__((address_space(1))) unsigned int*)g,
        (__attribute__((address_space(3))) unsigned int*)l, 16, 0, 0);
}

// ---------------------------------------------------------------------------
// K0: weight packing.
// Bg[kc][q][n'][8]: gate-interleaved level weights. k = kc*32+q*8+j;
//   n' = 4m+g: g<3 -> Wiouh[k][g*150+m], g==3 -> Wfh[k][m]; pad -> 0.
// Bx[kc][q][n][8]: leaf weights (plain n).
// ---------------------------------------------------------------------------
__global__ __launch_bounds__(256) void prep_kernel(
    const float* __restrict__ Wioux, const float* __restrict__ Wiouh,
    const float* __restrict__ Wfh, short* __restrict__ Bg, short* __restrict__ Bx)
{
    const int tid = blockIdx.x * blockDim.x + threadIdx.x;
    const int nthr = gridDim.x * blockDim.x;
    const int tot1 = GKC_ * GCH_;
    for (int idx = tid; idx < tot1; idx += nthr) {
        const int kc = idx / GCH_;
        int rem = idx % GCH_;
        const int q = rem / GQS_; rem %= GQS_;
        const int n = rem / 8, j = rem % 8;
        const int k = kc * 32 + q * 8 + j;
        const int m = n >> 2, g = n & 3;
        float v = 0.0f;
        if (k < M_ && m < M_)
            v = (g < 3) ? Wiouh[k * 450 + g * 150 + m] : Wfh[k * M_ + m];
        Bg[idx] = f2bs(v);
    }
    const int tot2 = LEAF_KC * LEAF_CH;
    for (int idx = tid; idx < tot2; idx += nthr) {
        const int kc = idx / LEAF_CH;
        int rem = idx % LEAF_CH;
        const int q = rem / LEAF_QS; rem %= LEAF_QS;
        const int n = rem / 8, j = rem % 8;
        const int k = kc * 32 + q * 8 + j;
        float v = (k < IN_ && n < 450) ? Wioux[k * 450 + n] : 0.0f;
        Bx[idx] = f2bs(v);
    }
}

// ---------------------------------------------------------------------------
// K1: leaf tables: emb @ Wioux -> LeafH/LeafC [V][160]
// ---------------------------------------------------------------------------
__global__ __launch_bounds__(512) void leaf_gemm(
    const float* __restrict__ emb, const short* __restrict__ Bx,
    const float* __restrict__ bioux, const float* __restrict__ biouh,
    short* __restrict__ LeafH, short* __restrict__ LeafC)
{
    __shared__ __align__(16) char smem[LEAF_CH * 2 + 64 * 64];
    short* Bs = (short*)smem;
    short* As = (short*)(smem + LEAF_CH * 2);
    float* Es = (float*)smem;

    const int t = threadIdx.x;
    const int row0 = blockIdx.x * 64;
    const int w = t >> 6, lane = t & 63;
    const int mt = w & 3, nt0 = (w >> 2) * LEAF_NT;
    const int lr = lane & 15, quad = lane >> 4;

    f32x4 acc[LEAF_NT];
    #pragma unroll
    for (int i = 0; i < LEAF_NT; i++) { acc[i][0] = 0; acc[i][1] = 0; acc[i][2] = 0; acc[i][3] = 0; }

    const int arow = t >> 3, apart = t & 7;
    const int av = row0 + arow;
    const int aq = apart >> 1, aj = (apart & 1) * 4;

    for (int kc = 0; kc < LEAF_KC; kc++) {
        const short* bsrc = Bx + (size_t)kc * LEAF_CH;
        #pragma unroll
        for (int i = 0; i < 3; i++)
            gl_lds16(bsrc + (i * 512 + t) * 8, Bs + (i * 512 + (t & ~63)) * 8);
        if (t < 384)
            gl_lds16(bsrc + (1536 + t) * 8, Bs + (1536 + (t & ~63)) * 8);
        {
            const int k0 = kc * 32 + apart * 4;
            float4 x = make_float4(0.f, 0.f, 0.f, 0.f);
            if (av < V_ && k0 < IN_) x = *(const float4*)&emb[(size_t)av * IN_ + k0];
            short4v s;
            s[0] = f2bs(x.x); s[1] = f2bs(x.y); s[2] = f2bs(x.z); s[3] = f2bs(x.w);
            *(short4v*)&As[aq * 512 + arow * 8 + aj] = s;
        }
        __syncthreads();
        bf16x8 a = *(const bf16x8*)&As[quad * 512 + (mt * 16 + lr) * 8];
        #pragma unroll
        for (int i = 0; i < LEAF_NT; i++) {
            bf16x8 b = *(const bf16x8*)&Bs[quad * LEAF_QS + ((nt0 + i) * 16 + lr) * 8];
            acc[i] = __builtin_amdgcn_mfma_f32_16x16x32_bf16(a, b, acc[i], 0, 0, 0);
        }
        __syncthreads();
    }

    for (int mc = 0; mc < 4; mc++) {
        if (mt == mc) {
            #pragma unroll
            for (int i = 0; i < LEAF_NT; i++) {
                const int col = (nt0 + i) * 16 + lr;
                #pragma unroll
                for (int r = 0; r < 4; r++) Es[(quad * 4 + r) * LEAF_N + col] = acc[i][r];
            }
        }
        __syncthreads();
        for (int p = t; p < 16 * KP_; p += 512) {
            const int rl = p / KP_, n = p % KP_;
            const int v = row0 + mc * 16 + rl;
            if (v < V_) {
                if (n < M_) {
                    const float i_ = Es[rl * LEAF_N + n]       + bioux[n]       + biouh[n];
                    const float o_ = Es[rl * LEAF_N + n + 150] + bioux[n + 150] + biouh[n + 150];
                    const float u_ = Es[rl * LEAF_N + n + 300] + bioux[n + 300] + biouh[n + 300];
                    const float c = sgm(i_) * tanh_f(u_);
                    const float h = sgm(o_) * tanh_f(c);
                    LeafH[(size_t)v * KP_ + n] = f2bs(h);
                    LeafC[(size_t)v * KP_ + n] = f2bs(c);
                } else {
                    LeafH[(size_t)v * KP_ + n] = 0;
                    LeafC[(size_t)v * KP_ + n] = 0;
                }
            }
        }
        __syncthreads();
    }
}

// ---------------------------------------------------------------------------
// K2: per-vocab level-0 tables, gate-interleaved output:
//   LeafE[v][4m+g]: g<3 -> raw iou contribution G; g==3 -> FC = sgm(F+bfh)*c
// ---------------------------------------------------------------------------
__global__ __launch_bounds__(512) void leafGF_gemm(
    const short* __restrict__ LeafH, const short* __restrict__ LeafC,
    const short* __restrict__ Bg, const float* __restrict__ bfh,
    short* __restrict__ LeafE)
{
    __shared__ __align__(16) char smem[GCH_ * 2 + 4096 + KP_ * 64 * 2 + 600];
    short* Bs   = (short*)smem;                       // 38912 B
    short* As   = (short*)(smem + GCH_ * 2);          // 4096 B
    short* CinS = (short*)(smem + GCH_ * 2 + 4096);   // 20480 B (LeafC rows)
    float* bfs  = (float*)(smem + GCH_ * 2 + 4096 + KP_ * 64 * 2);
    short* Os   = Bs;

    const int t = threadIdx.x;
    const int v0 = blockIdx.x * 64;
    const int w = t >> 6, lane = t & 63;
    const int mt = w & 3, nt0 = (w >> 2) * GNT_;
    const int lr = lane & 15, quad = lane >> 4;
    const int c = lane & 15;

    if (t < 150) bfs[t] = bfh[t];
    // CinS: 64 rows x 160 shorts = 10240 shorts = 1280 lane-loads (NOT 2560!)
    const short* csrc = LeafC + (size_t)v0 * KP_;
    #pragma unroll
    for (int i = 0; i < 2; i++)
        gl_lds16(csrc + (i * 512 + t) * 8, CinS + (i * 512 + (t & ~63)) * 8);
    if (t < 256)
        gl_lds16(csrc + (1024 + t) * 8, CinS + (1024 + (t & ~63)) * 8);

    f32x4 acc[GNT_];
    #pragma unroll
    for (int i = 0; i < GNT_; i++) { acc[i][0] = 0; acc[i][1] = 0; acc[i][2] = 0; acc[i][3] = 0; }

    const int arow = t & 63, apart = t >> 6;
    const size_t srow = (size_t)((v0 + arow < V_) ? (v0 + arow) : 0);
    const short* asrc = LeafH + srow * KP_ + apart * 8;

    for (int kc = 0; kc < GKC_; kc++) {
        const short* bsrc = Bg + (size_t)kc * GCH_;
        #pragma unroll
        for (int i = 0; i < 4; i++)
            gl_lds16(bsrc + (i * 512 + t) * 8, Bs + (i * 512 + (t & ~63)) * 8);
        if (t < 384)
            gl_lds16(bsrc + (2048 + t) * 8, Bs + (2048 + (t & ~63)) * 8);
        if (t < 256)
            gl_lds16(asrc + kc * 32, As + (t & ~63) * 8);
        __syncthreads();
        bf16x8 a = *(const bf16x8*)&As[quad * 512 + (mt * 16 + lr) * 8];
        #pragma unroll
        for (int i = 0; i < GNT_; i++) {
            bf16x8 b = *(const bf16x8*)&Bs[quad * GQS_ + ((nt0 + i) * 16 + lr) * 8];
            acc[i] = __builtin_amdgcn_mfma_f32_16x16x32_bf16(a, b, acc[i], 0, 0, 0);
        }
        __syncthreads();
    }

    // two 32-row phases: in-register epilogue -> Os -> coalesced global
    for (int ph = 0; ph < 2; ph++) {
        if ((mt >> 1) == ph) {
            const int rbase = 16 * (mt & 1) + 4 * quad;
            #pragma unroll
            for (int i = 0; i < GNT_; i++) {
                const int col = (nt0 + i) * 16 + c;
                const int m = col >> 2, g = col & 3;
                #pragma unroll
                for (int r = 0; r < 4; r++) {
                    short ov;
                    if (g == 3) {
                        if (m < M_) {
                            const float cc = bs2f(CinS[(32 * ph + rbase + r) * KP_ + m]);
                            ov = f2bs(sgm(acc[i][r] + bfs[m]) * cc);
                        } else ov = 0;
                    } else ov = f2bs(acc[i][r]);
                    Os[(rbase + r) * GN_ + col] = ov;
                }
            }
        }
        __syncthreads();
        const int vb = v0 + 32 * ph;
        const int4* os4 = (const int4*)Os;
        for (int u = t; u < 2432; u += 512) {
            const int row = u / 76;
            if (vb + row < V_)
                ((int4*)(LeafE + (size_t)(vb + row) * GN_))[u - row * 76] = os4[u];
        }
        __syncthreads();
    }
}

// ---------------------------------------------------------------------------
// Shared in-register LSTM epilogue for level GEMMs (gate-interleaved C).
// ---------------------------------------------------------------------------
__device__ __forceinline__ void level_epilogue(
    const f32x4* acc, int mt, int nt0, int lane,
    const short* CinS, const float* bias_s, short* Hs, short* Cs)
{
    const int q = lane >> 4, c = lane & 15, g = c & 3, lb = lane & ~3;
    #pragma unroll
    for (int i = 0; i < GNT_; i++) {
        const int col = (nt0 + i) * 16 + c;
        const int m = col >> 2;
        const float vA = acc[i][0] + acc[i][1];
        const float vB = acc[i][2] + acc[i][3];
        const float iA = __shfl(vA, lb), oA = __shfl(vA, lb + 1), uA = __shfl(vA, lb + 2);
        const float iB = __shfl(vB, lb), oB = __shfl(vB, lb + 1), uB = __shfl(vB, lb + 2);
        const float fA0 = __shfl(acc[i][0], lb + 3), fA1 = __shfl(acc[i][1], lb + 3);
        const float fB0 = __shfl(acc[i][2], lb + 3), fB1 = __shfl(acc[i][3], lb + 3);
        if (g < 2 && m < M_) {
            const float iv = g ? iB : iA, ov = g ? oB : oA, uv = g ? uB : uA;
            const float fl = g ? fB0 : fA0, fr = g ? fB1 : fA1;
            const int node = 8 * mt + 2 * q + g;
            const int ch = 16 * mt + 4 * q + 2 * g;
            const float cl = bs2f(CinS[ch * KP_ + m]);
            const float cr = bs2f(CinS[(ch + 1) * KP_ + m]);
            const float bf = bias_s[450 + m];
            const float cv = sgm(iv + bias_s[m]) * tanh_f(uv + bias_s[m + 300])
                           + sgm(fl + bf) * cl + sgm(fr + bf) * cr;
            const float hv = sgm(ov + bias_s[m + 150]) * tanh_f(cv);
            Hs[node * KP_ + m] = f2bs(hv);
            Cs[node * KP_ + m] = f2bs(cv);
        }
    }
}

// ---------------------------------------------------------------------------
// K3: level 1 with fused level-0 gather (A computed in-block from LeafE).
// ---------------------------------------------------------------------------
__global__ __launch_bounds__(512) void level1_fused(
    const int* __restrict__ ltok, const int* __restrict__ rtok,
    const short* __restrict__ LeafE, const short* __restrict__ Bg,
    const float* __restrict__ biouh, const float* __restrict__ bfh,
    short* __restrict__ Hout, short* __restrict__ Cout)
{
    __shared__ __align__(16) char smem[GCH_ * 2 + 20480 + 20480 + 2400 + 512];
    short* Bs     = (short*)smem;                              // 38912 B
    short* AsF    = (short*)(smem + GCH_ * 2);                 // 20480 B persistent A
    short* CinS   = (short*)(smem + GCH_ * 2 + 20480);         // 20480 B
    float* bias_s = (float*)(smem + GCH_ * 2 + 40960);         // 2400 B
    int*   toks   = (int*)(smem + GCH_ * 2 + 43360);           // 512 B
    short* Hs = Bs;
    short* Cs = Bs + 32 * KP_;

    const int t = threadIdx.x;
    const int out0 = blockIdx.x * 32;
    const int w = t >> 6, lane = t & 63;
    const int mt = w & 3, nt0 = (w >> 2) * GNT_;
    const int lr = lane & 15, quad = lane >> 4;

    if (t < 600) bias_s[t] = (t < 450) ? biouh[t] : bfh[t - 450];
    if (t < 128) {
        const int idx = blockIdx.x * 128 + t;
        toks[t] = (idx < B_ * L_) ? ltok[idx] : rtok[idx - B_ * L_];
    }
    __syncthreads();

    // ---- fused level-0: compute 64 node h/c rows into AsF / CinS ----
    {
        const int row = t >> 3, qs = t & 7;
        const short* el = LeafE + (size_t)toks[2 * row] * GN_;
        const short* er = LeafE + (size_t)toks[2 * row + 1] * GN_;
        #pragma unroll
        for (int s = 0; s < 5; s++) {
            const int Q = qs + 8 * s;          // m-quad 0..39
            short4v hq = {0, 0, 0, 0}, cq = {0, 0, 0, 0};
            if (Q < 38) {
                union { int4 v[2]; short s16[16]; } ue, ur;
                ue.v[0] = *(const int4*)(el + Q * 16);
                ue.v[1] = *(const int4*)(el + Q * 16 + 8);
                ur.v[0] = *(const int4*)(er + Q * 16);
                ur.v[1] = *(const int4*)(er + Q * 16 + 8);
                #pragma unroll
                for (int jj = 0; jj < 4; jj++) {
                    const int m = 4 * Q + jj;
                    if (m < M_) {
                        const float i_ = bs2f(ue.s16[4 * jj])     + bs2f(ur.s16[4 * jj])     + bias_s[m];
                        const float o_ = bs2f(ue.s16[4 * jj + 1]) + bs2f(ur.s16[4 * jj + 1]) + bias_s[m + 150];
                        const float u_ = bs2f(ue.s16[4 * jj + 2]) + bs2f(ur.s16[4 * jj + 2]) + bias_s[m + 300];
                        const float fc = bs2f(ue.s16[4 * jj + 3]) + bs2f(ur.s16[4 * jj + 3]);
                        const float cv = sgm(i_) * tanh_f(u_) + fc;
                        const float hv = sgm(o_) * tanh_f(cv);
                        hq[jj] = f2bs(hv); cq[jj] = f2bs(cv);
                    }
                }
            }
            const int m0 = 4 * Q;
            const int kc = m0 >> 5, q = (m0 >> 3) & 3, j0 = m0 & 7;
            *(short4v*)&AsF[(kc * 4 + q) * 512 + row * 8 + j0] = hq;
            *(short4v*)&CinS[row * KP_ + m0] = cq;
        }
    }

    f32x4 acc[GNT_];
    #pragma unroll
    for (int i = 0; i < GNT_; i++) { acc[i][0] = 0; acc[i][1] = 0; acc[i][2] = 0; acc[i][3] = 0; }

    for (int kc = 0; kc < GKC_; kc++) {
        const short* bsrc = Bg + (size_t)kc * GCH_;
        #pragma unroll
        for (int i = 0; i < 4; i++)
            gl_lds16(bsrc + (i * 512 + t) * 8, Bs + (i * 512 + (t & ~63)) * 8);
        if (t < 384)
            gl_lds16(bsrc + (2048 + t) * 8, Bs + (2048 + (t & ~63)) * 8);
        __syncthreads();
        bf16x8 a = *(const bf16x8*)&AsF[kc * 2048 + quad * 512 + (mt * 16 + lr) * 8];
        #pragma unroll
        for (int i = 0; i < GNT_; i++) {
            bf16x8 b = *(const bf16x8*)&Bs[quad * GQS_ + ((nt0 + i) * 16 + lr) * 8];
            acc[i] = __builtin_amdgcn_mfma_f32_16x16x32_bf16(a, b, acc[i], 0, 0, 0);
        }
        __syncthreads();
    }

    if (t < 320) { const int node = t / 10, mm = 150 + t % 10;
                   Hs[node * KP_ + mm] = 0; Cs[node * KP_ + mm] = 0; }
    level_epilogue(acc, mt, nt0, lane, CinS, bias_s, Hs, Cs);
    __syncthreads();
    int4* Hg = (int4*)(Hout + (size_t)out0 * KP_);
    int4* Cg = (int4*)(Cout + (size_t)out0 * KP_);
    const int4* hs4 = (const int4*)Hs;
    const int4* cs4 = (const int4*)Cs;
    for (int u = t; u < 1280; u += 512) {
        if (u < 640) Hg[u] = hs4[u]; else Cg[u - 640] = cs4[u - 640];
    }
}

// ---------------------------------------------------------------------------
// K4: internal levels 2..5 (A and Cin from global state buffers).
// ---------------------------------------------------------------------------
__global__ __launch_bounds__(512) void level_gemm(
    const short* __restrict__ Hin, const short* __restrict__ Cin,
    const short* __restrict__ Bg,
    const float* __restrict__ biouh, const float* __restrict__ bfh,
    short* __restrict__ Hout, short* __restrict__ Cout)
{
    __shared__ __align__(16) char smem[GCH_ * 2 + 4096 + 20480 + 2400];
    short* Bs     = (short*)smem;
    short* As     = (short*)(smem + GCH_ * 2);
    short* CinS   = (short*)(smem + GCH_ * 2 + 4096);
    float* bias_s = (float*)(smem + GCH_ * 2 + 4096 + 20480);
    short* Hs = Bs;
    short* Cs = Bs + 32 * KP_;

    const int t = threadIdx.x;
    const int row0 = blockIdx.x * 64, out0 = blockIdx.x * 32;
    const int w = t >> 6, lane = t & 63;
    const int mt = w & 3, nt0 = (w >> 2) * GNT_;
    const int lr = lane & 15, quad = lane >> 4;

    if (t < 600) bias_s[t] = (t < 450) ? biouh[t] : bfh[t - 450];
    // CinS: 10240 shorts = 1280 lane-loads (2 full rounds + t<256 tail)
    const short* csrc = Cin + (size_t)row0 * KP_;
    #pragma unroll
    for (int i = 0; i < 2; i++)
        gl_lds16(csrc + (i * 512 + t) * 8, CinS + (i * 512 + (t & ~63)) * 8);
    if (t < 256)
        gl_lds16(csrc + (1024 + t) * 8, CinS + (1024 + (t & ~63)) * 8);

    f32x4 acc[GNT_];
    #pragma unroll
    for (int i = 0; i < GNT_; i++) { acc[i][0] = 0; acc[i][1] = 0; acc[i][2] = 0; acc[i][3] = 0; }

    const short* asrc = Hin + (size_t)(row0 + (t & 63)) * KP_ + (t >> 6) * 8;

    for (int kc = 0; kc < GKC_; kc++) {
        const short* bsrc = Bg + (size_t)kc * GCH_;
        #pragma unroll
        for (int i = 0; i < 4; i++)
            gl_lds16(bsrc + (i * 512 + t) * 8, Bs + (i * 512 + (t & ~63)) * 8);
        if (t < 384)
            gl_lds16(bsrc + (2048 + t) * 8, Bs + (2048 + (t & ~63)) * 8);
        if (t < 256)
            gl_lds16(asrc + kc * 32, As + (t & ~63) * 8);
        __syncthreads();
        bf16x8 a = *(const bf16x8*)&As[quad * 512 + (mt * 16 + lr) * 8];
        #pragma unroll
        for (int i = 0; i < GNT_; i++) {
            bf16x8 b = *(const bf16x8*)&Bs[quad * GQS_ + ((nt0 + i) * 16 + lr) * 8];
            acc[i] = __builtin_amdgcn_mfma_f32_16x16x32_bf16(a, b, acc[i], 0, 0, 0);
        }
        __syncthreads();
    }

    if (t < 320) { const int node = t / 10, mm = 150 + t % 10;
                   Hs[node * KP_ + mm] = 0; Cs[node * KP_ + mm] = 0; }
    level_epilogue(acc, mt, nt0, lane, CinS, bias_s, Hs, Cs);
    __syncthreads();
    int4* Hg = (int4*)(Hout + (size_t)out0 * KP_);
    int4* Cg = (int4*)(Cout + (size_t)out0 * KP_);
    const int4* hs4 = (const int4*)Hs;
    const int4* cs4 = (const int4*)Cs;
    for (int u = t; u < 1280; u += 512) {
        if (u < 640) Hg[u] = hs4[u]; else Cg[u - 640] = cs4[u - 640];
    }
}

// ---------------------------------------------------------------------------
// K5: similarity head (one wave per pair).
// ---------------------------------------------------------------------------
__global__ __launch_bounds__(64) void head_kernel(
    const short* __restrict__ RootH,
    const float* __restrict__ Wh, const float* __restrict__ bh,
    const float* __restrict__ Wp, const float* __restrict__ bp,
    float* __restrict__ out)
{
    __shared__ float vec[2 * M_];
    __shared__ float mid[HID_];
    __shared__ float lg[NC_];
    __shared__ float lse;

    const int b = blockIdx.x;
    const int t = threadIdx.x;
    const short* lh = RootH + (size_t)b * KP_;
    const short* rh = RootH + (size_t)(B_ + b) * KP_;

    for (int i = t; i < M_; i += 64) {
        const float a = bs2f(lh[i]), c = bs2f(rh[i]);
        vec[i]      = a * c;
        vec[M_ + i] = fabsf(a - c);
    }
    __syncthreads();

    for (int j = t; j < HID_; j += 64) {
        float acc = bh[j];
        for (int k = 0; k < 2 * M_; k++) acc += vec[k] * Wh[k * HID_ + j];
        mid[j] = sgm(acc);
    }
    __syncthreads();

    if (t < NC_) {
        float acc = bp[t];
        for (int k = 0; k < HID_; k++) acc += mid[k] * Wp[k * NC_ + t];
        lg[t] = acc;
    }
    __syncthreads();

    if (t == 0) {
        float mx = lg[0];
        for (int i = 1; i < NC_; i++) mx = fmaxf(mx, lg[i]);
        float s = 0.0f;
        for (int i = 0; i < NC_; i++) s += expf(lg[i] - mx);
        lse = mx + logf(s);
    }
    __syncthreads();

    if (t < NC_) out[b * NC_ + t] = lg[t] - lse;
}

// ---------------------------------------------------------------------------
extern "C" void kernel_launch(void* const* d_in, const int* in_sizes, int n_in,
                              void* d_out, int out_size, void* d_ws, size_t ws_size,
                              hipStream_t stream)
{
    const int*   ltok  = (const int*)d_in[0];
    const int*   rtok  = (const int*)d_in[1];
    const float* emb   = (const float*)d_in[2];
    const float* Wioux = (const float*)d_in[3];
    const float* bioux = (const float*)d_in[4];
    const float* Wiouh = (const float*)d_in[5];
    const float* biouh = (const float*)d_in[6];
    const float* Wfh   = (const float*)d_in[9];
    const float* bfh   = (const float*)d_in[10];
    const float* Wh    = (const float*)d_in[11];
    const float* bh    = (const float*)d_in[12];
    const float* Wp    = (const float*)d_in[13];
    const float* bp    = (const float*)d_in[14];
    float* out = (float*)d_out;

    char* ws = (char*)d_ws;
    size_t off = 0;
    auto carve = [&](size_t bytes) { char* p = ws + off; off += (bytes + 255) & ~(size_t)255; return p; };
    short* Bg    = (short*)carve((size_t)GKC_ * GCH_ * 2);
    short* Bx    = (short*)carve((size_t)LEAF_KC * LEAF_CH * 2);
    short* LeafH = (short*)carve((size_t)V_ * KP_ * 2);      // 16 MB
    short* LeafC = (short*)carve((size_t)V_ * KP_ * 2);      // 16 MB
    short* LeafE = (short*)carve((size_t)V_ * GN_ * 2);      // 60.8 MB
    short* HA    = (short*)carve((size_t)65536 * KP_ * 2);   // 21 MB
    short* CA    = (short*)carve((size_t)65536 * KP_ * 2);   // 21 MB
    short* HB    = (short*)carve((size_t)32768 * KP_ * 2);   // 10.5 MB
    short* CB    = (short*)carve((size_t)32768 * KP_ * 2);   // 10.5 MB

    hipLaunchKernelGGL(prep_kernel, dim3(128), dim3(256), 0, stream, Wioux, Wiouh, Wfh, Bg, Bx);
    hipLaunchKernelGGL(leaf_gemm, dim3((V_ + 63) / 64), dim3(512), 0, stream,
                       emb, Bx, bioux, biouh, LeafH, LeafC);
    hipLaunchKernelGGL(leafGF_gemm, dim3((V_ + 63) / 64), dim3(512), 0, stream,
                       LeafH, LeafC, Bg, bfh, LeafE);
    // level 1 (fused level-0 gather): 131072 nodes -> 65536 rows
    hipLaunchKernelGGL(level1_fused, dim3(2048), dim3(512), 0, stream,
                       ltok, rtok, LeafE, Bg, biouh, bfh, HA, CA);
    // levels 2..5
    hipLaunchKernelGGL(level_gemm, dim3(1024), dim3(512), 0, stream,
                       HA, CA, Bg, biouh, bfh, HB, CB);
    hipLaunchKernelGGL(level_gemm, dim3(512), dim3(512), 0, stream,
                       HB, CB, Bg, biouh, bfh, HA, CA);
    hipLaunchKernelGGL(level_gemm, dim3(256), dim3(512), 0, stream,
                       HA, CA, Bg, biouh, bfh, HB, CB);
    hipLaunchKernelGGL(level_gemm, dim3(128), dim3(512), 0, stream,
                       HB, CB, Bg, biouh, bfh, HA, CA);
    hipLaunchKernelGGL(head_kernel, dim3(B_), dim3(64), 0, stream, HA, Wh, bh, Wp, bp, out);
}